// Round 7
// baseline (484.191 us; speedup 1.0000x reference)
//
#include <hip/hip_runtime.h>
#include <cstddef>
#include <math.h>

#define B_ 8
#define C_ 512
#define L_ 2048
#define D_ 64

typedef __bf16 bf16x8 __attribute__((ext_vector_type(8)));
typedef __bf16 bf16x4 __attribute__((ext_vector_type(4)));
typedef float f32x4 __attribute__((ext_vector_type(4)));

#define MFMA16 __builtin_amdgcn_mfma_f32_16x16x32_bf16

__device__ __forceinline__ void async_lds16(const void* g, void* l) {
  __builtin_amdgcn_global_load_lds(
      (const __attribute__((address_space(1))) void*)g,
      (__attribute__((address_space(3))) void*)l, 16, 0, 0);
}

// ---------------------------------------------------------------------------
// x (B,C,L) fp32 -> xT (B,L,C) bf16, 32x32 LDS tile
// ---------------------------------------------------------------------------
__global__ __launch_bounds__(256) void transpose_cvt(const float* __restrict__ x,
                                                     __bf16* __restrict__ xT) {
  __shared__ float t[32][33];
  const int b = blockIdx.z;
  const int l0 = blockIdx.x * 32, c0 = blockIdx.y * 32;
  const int tx = threadIdx.x & 31, ty = threadIdx.x >> 5;  // ty 0..7
  const float* xb = x + (size_t)b * C_ * L_;
#pragma unroll
  for (int r = 0; r < 4; ++r)
    t[ty + r * 8][tx] = xb[(size_t)(c0 + ty + r * 8) * L_ + l0 + tx];
  __syncthreads();
  __bf16* xTb = xT + (size_t)b * L_ * C_;
#pragma unroll
  for (int r = 0; r < 4; ++r)
    xTb[(size_t)(l0 + ty + r * 8) * C_ + c0 + tx] = (__bf16)t[tx][ty + r * 8];
}

// ---------------------------------------------------------------------------
// Stack [Wq;Wk;Wv] -> W bf16 (640x512), [bq;bk;bv] -> bias fp32 (640)
// ---------------------------------------------------------------------------
__global__ __launch_bounds__(256) void prep_qkv(
    const float* __restrict__ Wq, const float* __restrict__ Wk,
    const float* __restrict__ Wv, const float* __restrict__ bq,
    const float* __restrict__ bk, const float* __restrict__ bv,
    __bf16* __restrict__ W, float* __restrict__ bias) {
  const int i = blockIdx.x * 256 + threadIdx.x;  // float4 index, 81920 total
  const int rq = 64 * 512 / 4;                   // 8192
  const int rk = 128 * 512 / 4;                  // 16384
  const float* src;
  int j;
  if (i < rq) {
    src = Wq; j = i;
  } else if (i < rk) {
    src = Wk; j = i - rq;
  } else {
    src = Wv; j = i - rk;
  }
  float4 v = ((const float4*)src)[j];
  bf16x4 h = {(__bf16)v.x, (__bf16)v.y, (__bf16)v.z, (__bf16)v.w};
  ((bf16x4*)W)[i] = h;
  if (blockIdx.x == 0) {
    for (int t = threadIdx.x; t < 640; t += 256)
      bias[t] = t < 64 ? bq[t] : (t < 128 ? bk[t - 64] : bv[t - 128]);
  }
}

// ---------------------------------------------------------------------------
// Unified MFMA bf16 gemm_bt: C[m,n] = sum_k W[m,k]*xT[n,k] + bias[m]
// M=640 stacked [q(64); k(64); v(512)], N=L, K=C. 128x128 tile, BK=32,
// XOR-swizzled LDS chunks. Epilogue routes rows to qh/kh/vh.
// ---------------------------------------------------------------------------
__global__ __launch_bounds__(256) void gemm_qkv(
    const __bf16* __restrict__ A, const __bf16* __restrict__ Bm,
    const float* __restrict__ bias, __bf16* __restrict__ qh,
    __bf16* __restrict__ kh, __bf16* __restrict__ vh) {
  __shared__ __align__(16) __bf16 Ash[128 * 32];
  __shared__ __align__(16) __bf16 Bsh[128 * 32];
  const int b = blockIdx.z;
  const int m0 = blockIdx.x * 128;
  const int n0 = blockIdx.y * 128;
  const int tid = threadIdx.x;
  const int w = tid >> 6, lane = tid & 63;
  const int wm = (w & 1) * 64, wn = (w >> 1) * 64;
  const int lm = lane & 15, q8 = lane >> 4;
  const int srow = lane >> 2;                      // row within 16-row group
  const int sk8 = (lane & 3) ^ ((lane >> 3) & 3);  // swizzled source chunk

  const __bf16* Bb = Bm + (size_t)b * L_ * C_;
  f32x4 acc[4][4] = {};

  for (int k0 = 0; k0 < C_; k0 += 32) {
#pragma unroll
    for (int t = 0; t < 2; ++t) {
      const int rb = (t * 4 + w) * 16;
      async_lds16(A + (size_t)(m0 + rb + srow) * C_ + k0 + sk8 * 8,
                  &Ash[rb * 32]);
      async_lds16(Bb + (size_t)(n0 + rb + srow) * C_ + k0 + sk8 * 8,
                  &Bsh[rb * 32]);
    }
    __syncthreads();
    const int swz = (q8 ^ ((lm >> 1) & 3)) * 8;
    bf16x8 afr[4], bfr[4];
#pragma unroll
    for (int i = 0; i < 4; ++i) {
      afr[i] = *(const bf16x8*)&Ash[(wm + i * 16 + lm) * 32 + swz];
      bfr[i] = *(const bf16x8*)&Bsh[(wn + i * 16 + lm) * 32 + swz];
    }
#pragma unroll
    for (int i = 0; i < 4; ++i)
#pragma unroll
      for (int j = 0; j < 4; ++j)
        acc[i][j] = MFMA16(afr[i], bfr[j], acc[i][j], 0, 0, 0);
    __syncthreads();
  }

#pragma unroll
  for (int i = 0; i < 4; ++i) {
#pragma unroll
    for (int j = 0; j < 4; ++j) {
      const int ng = n0 + wn + j * 16 + lm;
      const int mg = m0 + wm + i * 16 + q8 * 4;  // global stacked row (4-group)
      if (mg < 128) {
        bf16x4 h;
#pragma unroll
        for (int r = 0; r < 4; ++r) h[r] = (__bf16)(acc[i][j][r] + bias[mg + r]);
        if (mg < 64)
          *(bf16x4*)&qh[((size_t)b * L_ + ng) * 64 + mg] = h;
        else
          *(bf16x4*)&kh[((size_t)b * L_ + ng) * 64 + mg - 64] = h;
      } else {
#pragma unroll
        for (int r = 0; r < 4; ++r)
          vh[((size_t)b * C_ + mg - 128 + r) * L_ + ng] =
              (__bf16)(acc[i][j][r] + bias[mg + r]);
      }
    }
  }
}

// ---------------------------------------------------------------------------
// Row sums of exp(QK^T) under causal+data mask -> sinv[b*L+l] = 1/rowsum.
// Identical QK/exp code path to attn_fused => bit-identical normalization.
// One block per 32-row stripe (balanced s mapping), k/mask double-buffered.
// ---------------------------------------------------------------------------
__global__ __launch_bounds__(256) void row_sums(
    const __bf16* __restrict__ q, const __bf16* __restrict__ k,
    const unsigned char* __restrict__ mask, float* __restrict__ sinv) {
  __shared__ __align__(16) __bf16 qs[32 * 64];
  __shared__ __align__(16) __bf16 ks[2][128 * 64];
  __shared__ __align__(16) unsigned char msk[2][32 * 128];
  __shared__ float sums[4][32];
  const int b = blockIdx.y;
  const int s = (b < 4) ? (int)blockIdx.x : 63 - (int)blockIdx.x;
  const int r0 = s * 32;
  const int T = (r0 + 31) / 128 + 1;
  const int tid = threadIdx.x;
  const int w = tid >> 6, lane = tid & 63;
  const int lm = lane & 15, q8 = lane >> 4;
  const __bf16* qb = q + (size_t)b * L_ * D_;
  const __bf16* kb = k + (size_t)b * L_ * D_;
  const int krow = lane >> 3;
  const int kk8 = (lane & 7) ^ ((lane >> 3) & 7);

  async_lds16(qb + (size_t)r0 * D_ + tid * 8, &qs[w * 512]);
#pragma unroll
  for (int r = 0; r < 4; ++r)
    async_lds16(kb + (size_t)(r * 32 + w * 8 + krow) * 64 + kk8 * 8,
                &ks[0][(r * 32 + w * 8) * 64]);
  async_lds16(mask + ((size_t)b * L_ + r0 + w * 8 + krow) * L_ + (lane & 7) * 16,
              &msk[0][w * 1024]);

  bf16x8 af[2][2];
  float rsum[2][4] = {};
  for (int t = 0; t < T; ++t) {
    const int t0 = t * 128, buf = t & 1;
    __syncthreads();
    if (t == 0) {
#pragma unroll
      for (int i = 0; i < 2; ++i)
#pragma unroll
        for (int kk = 0; kk < 2; ++kk)
          af[i][kk] = *(const bf16x8*)&qs[(i * 16 + lm) * 64 + kk * 32 + q8 * 8];
    }
    if (t + 1 < T) {
      const int nt0 = t0 + 128, nb = (t + 1) & 1;
#pragma unroll
      for (int r = 0; r < 4; ++r)
        async_lds16(kb + (size_t)(nt0 + r * 32 + w * 8 + krow) * 64 + kk8 * 8,
                    &ks[nb][(r * 32 + w * 8) * 64]);
      async_lds16(mask + ((size_t)b * L_ + r0 + w * 8 + krow) * L_ + nt0 +
                      (lane & 7) * 16,
                  &msk[nb][w * 1024]);
    }
    f32x4 acc[2][2] = {};
#pragma unroll
    for (int kk = 0; kk < 2; ++kk) {
#pragma unroll
      for (int j = 0; j < 2; ++j) {
        const int n = w * 32 + j * 16 + lm;
        const int k8i = kk * 4 + q8;
        bf16x8 bf = *(const bf16x8*)&ks[buf][n * 64 + ((k8i ^ (n & 7)) * 8)];
#pragma unroll
        for (int i = 0; i < 2; ++i)
          acc[i][j] = MFMA16(af[i][kk], bf, acc[i][j], 0, 0, 0);
      }
    }
#pragma unroll
    for (int i = 0; i < 2; ++i)
#pragma unroll
      for (int j = 0; j < 2; ++j)
#pragma unroll
        for (int r = 0; r < 4; ++r) {
          const int lr = i * 16 + q8 * 4 + r;
          const int mcol = w * 32 + j * 16 + lm;
          const int l = r0 + lr, m = t0 + mcol;
          const bool ok = (m <= l) && (msk[buf][lr * 128 + mcol] == 0);
          rsum[i][r] += ok ? __expf(acc[i][j][r]) : 0.f;
        }
  }
  // reduce across the 16 col-lanes, then across the 4 waves
#pragma unroll
  for (int i = 0; i < 2; ++i)
#pragma unroll
    for (int r = 0; r < 4; ++r) {
      float vv = rsum[i][r];
      vv += __shfl_xor(vv, 1);
      vv += __shfl_xor(vv, 2);
      vv += __shfl_xor(vv, 4);
      vv += __shfl_xor(vv, 8);
      if (lm == 0) sums[w][i * 16 + q8 * 4 + r] = vv;
    }
  __syncthreads();
  if (tid < 32)
    sinv[(size_t)b * L_ + r0 + tid] =
        1.f / (sums[0][tid] + sums[1][tid] + sums[2][tid] + sums[3][tid]);
}

// ---------------------------------------------------------------------------
// Single-pass fused attention. Round-7 delta vs round 6 (119.5us): V register
// prefetch in two 64-VGPR groups (cf0-3 issued before QK, hidden under
// QK+exp; cf4-7 after the exp/att section), enabled by amdgpu_waves_per_eu
// (2,2) so the allocator may use up to 256 VGPRs (LDS already caps us at
// 2 blocks/CU = 8 waves, so the registers are free). Round-5's version of
// this was a silent no-op: launch_bounds(256,2) kept the allocator at 128
// VGPR and the loads were sunk back into the PV loop (VGPR_Count stayed
// 128) -- its regression was the nt-store HBM amplification, now removed.
// Mid-tile barrier stays lgkmcnt-only (round-6 win).
// ---------------------------------------------------------------------------
__global__ __attribute__((amdgpu_waves_per_eu(2, 2)))
__launch_bounds__(256) void attn_fused(
    const __bf16* __restrict__ q, const __bf16* __restrict__ k,
    const __bf16* __restrict__ v, const unsigned char* __restrict__ mask,
    const float* __restrict__ sinv, float* __restrict__ att,
    float* __restrict__ out) {
  __shared__ __align__(16) __bf16 qs[32 * 64];              // 4 KB
  __shared__ __align__(16) __bf16 ks[2][128 * 64];          // 32 KB, swizzled
  __shared__ __align__(16) unsigned char msk[2][32 * 128];  // 8 KB
  __shared__ __align__(16) __bf16 Ps[32 * 136];             // 8.5 KB, padded
  const int b = blockIdx.y;
  const int s = (b < 4) ? (int)blockIdx.x : 63 - (int)blockIdx.x;  // balance
  const int r0 = s * 32;
  const int T = (r0 + 31) / 128 + 1;  // tiles with any unmasked col
  const int tid = threadIdx.x;
  const int w = tid >> 6, lane = tid & 63;
  const int lm = lane & 15, q8 = lane >> 4;
  const __bf16* qb = q + (size_t)b * L_ * D_;
  const __bf16* kb = k + (size_t)b * L_ * D_;
  const __bf16* vb = v + (size_t)b * C_ * L_;
  const int krow = lane >> 3;
  const int kk8 = (lane & 7) ^ ((lane >> 3) & 7);

  float inv[2][4];
#pragma unroll
  for (int i = 0; i < 2; ++i)
#pragma unroll
    for (int r = 0; r < 4; ++r)
      inv[i][r] = sinv[(size_t)b * L_ + r0 + i * 16 + q8 * 4 + r];

  bf16x8 af[2][2];
  f32x4 accO[2][8] = {};  // 32 rows x 128 channels per wave

  async_lds16(qb + (size_t)r0 * D_ + tid * 8, &qs[w * 512]);
#pragma unroll
  for (int r = 0; r < 4; ++r)
    async_lds16(kb + (size_t)(r * 32 + w * 8 + krow) * 64 + kk8 * 8,
                &ks[0][(r * 32 + w * 8) * 64]);
  async_lds16(mask + ((size_t)b * L_ + r0 + w * 8 + krow) * L_ + (lane & 7) * 16,
              &msk[0][w * 1024]);

  for (int t = 0; t < T; ++t) {
    const int t0 = t * 128, buf = t & 1;
    __syncthreads();  // buf tiles (and on t==0: qs) ready
    if (t == 0) {
#pragma unroll
      for (int i = 0; i < 2; ++i)
#pragma unroll
        for (int kk = 0; kk < 2; ++kk)
          af[i][kk] = *(const bf16x8*)&qs[(i * 16 + lm) * 64 + kk * 32 + q8 * 8];
    }
    if (t + 1 < T) {  // prefetch next tile into the other buffer
      const int nt0 = t0 + 128, nb = (t + 1) & 1;
#pragma unroll
      for (int r = 0; r < 4; ++r)
        async_lds16(kb + (size_t)(nt0 + r * 32 + w * 8 + krow) * 64 + kk8 * 8,
                    &ks[nb][(r * 32 + w * 8) * 64]);
      async_lds16(mask + ((size_t)b * L_ + r0 + w * 8 + krow) * L_ + nt0 +
                      (lane & 7) * 16,
                  &msk[nb][w * 1024]);
    }
    // ---- V register prefetch, group A (cf0-3): issued before QK so the
    // L2/L3 latency hides under QK+exp (~3000 cy). Pinned by sched_barrier.
    bf16x8 vfr[8][4];
#pragma unroll
    for (int cf = 0; cf < 4; ++cf) {
      const __bf16* vp = vb + (size_t)(w * 128 + cf * 16 + lm) * L_ + t0 + q8 * 8;
#pragma unroll
      for (int kk = 0; kk < 4; ++kk) vfr[cf][kk] = *(const bf16x8*)(vp + kk * 32);
    }
    __builtin_amdgcn_sched_barrier(0);
    // ---- QK^T MFMA (swizzled B-frag reads) ----
    f32x4 acc[2][2] = {};
#pragma unroll
    for (int kk = 0; kk < 2; ++kk) {
#pragma unroll
      for (int j = 0; j < 2; ++j) {
        const int n = w * 32 + j * 16 + lm;
        const int k8i = kk * 4 + q8;
        bf16x8 bf = *(const bf16x8*)&ks[buf][n * 64 + ((k8i ^ (n & 7)) * 8)];
#pragma unroll
        for (int i = 0; i < 2; ++i)
          acc[i][j] = MFMA16(af[i][kk], bf, acc[i][j], 0, 0, 0);
      }
    }
    // ---- exp + mask + att write (normalized) + P to LDS (unnormalized) ----
#pragma unroll
    for (int i = 0; i < 2; ++i)
#pragma unroll
      for (int j = 0; j < 2; ++j)
#pragma unroll
        for (int r = 0; r < 4; ++r) {
          const int lr = i * 16 + q8 * 4 + r;
          const int mcol = w * 32 + j * 16 + lm;
          const int l = r0 + lr, m = t0 + mcol;
          const bool ok = (m <= l) && (msk[buf][lr * 128 + mcol] == 0);
          const float p = ok ? __expf(acc[i][j][r]) : 0.f;
          att[((size_t)b * L_ + l) * L_ + m] = p * inv[i][r];
          Ps[lr * 136 + mcol] = (__bf16)p;
        }
    // ---- V register prefetch, group B (cf4-7): retires under PV's group A ---
#pragma unroll
    for (int cf = 4; cf < 8; ++cf) {
      const __bf16* vp = vb + (size_t)(w * 128 + cf * 16 + lm) * L_ + t0 + q8 * 8;
#pragma unroll
      for (int kk = 0; kk < 4; ++kk) vfr[cf][kk] = *(const bf16x8*)(vp + kk * 32);
    }
    // Ps-ready barrier: LDS-only drain; att stores + k/mask prefetches + V
    // loads stay in flight (no vmcnt(0) here).
    asm volatile("s_waitcnt lgkmcnt(0)\n\ts_barrier" ::: "memory");
    __builtin_amdgcn_sched_barrier(0);
    // ---- PV: A = P rows (32 x 128k), B = v fragments (registers) ----
#pragma unroll
    for (int kk = 0; kk < 4; ++kk) {
      bf16x8 pa[2];
#pragma unroll
      for (int i = 0; i < 2; ++i)
        pa[i] = *(const bf16x8*)&Ps[(i * 16 + lm) * 136 + kk * 32 + q8 * 8];
#pragma unroll
      for (int cf = 0; cf < 8; ++cf) {
#pragma unroll
        for (int i = 0; i < 2; ++i)
          accO[i][cf] = MFMA16(pa[i], vfr[cf][kk], accO[i][cf], 0, 0, 0);
      }
    }
  }

  // ---- out epilogue: scale by inv[row], vectorized along l ----
#pragma unroll
  for (int i = 0; i < 2; ++i)
#pragma unroll
    for (int cf = 0; cf < 8; ++cf) {
      const int c = w * 128 + cf * 16 + lm;
      f32x4 o;
      o[0] = accO[i][cf][0] * inv[i][0];
      o[1] = accO[i][cf][1] * inv[i][1];
      o[2] = accO[i][cf][2] * inv[i][2];
      o[3] = accO[i][cf][3] * inv[i][3];
      *(f32x4*)(out + ((size_t)b * C_ + c) * L_ + r0 + i * 16 + q8 * 4) = o;
    }

  // ---- zero-fill att cols [T*128, L) of this stripe ----
  const f32x4 z4 = {0.f, 0.f, 0.f, 0.f};
  for (int rr = 0; rr < 32; ++rr) {
    float* arow = att + ((size_t)b * L_ + r0 + rr) * L_;
    for (int c = T * 128 + tid * 4; c < L_; c += 1024) *(f32x4*)&arow[c] = z4;
  }
}

// ---------------------------------------------------------------------------
extern "C" void kernel_launch(void* const* d_in, const int* in_sizes, int n_in,
                              void* d_out, int out_size, void* d_ws,
                              size_t ws_size, hipStream_t stream) {
  const float* x = (const float*)d_in[0];
  const unsigned char* dmask = (const unsigned char*)d_in[1];
  const float* Wq = (const float*)d_in[2];
  const float* bq = (const float*)d_in[3];
  const float* Wk = (const float*)d_in[4];
  const float* bk = (const float*)d_in[5];
  const float* Wv = (const float*)d_in[6];
  const float* bv = (const float*)d_in[7];

  float* out = (float*)d_out;               // (B, C, L)
  float* att = out + (size_t)B_ * C_ * L_;  // (B, L, L)

  __bf16* qh = (__bf16*)d_ws;                    // (B,L,64)   2 MB
  __bf16* kh = qh + (size_t)B_ * L_ * D_;        // (B,L,64)   2 MB
  __bf16* xTh = kh + (size_t)B_ * L_ * D_;       // (B,L,C)   16.8 MB
  __bf16* vh = xTh + (size_t)B_ * L_ * C_;       // (B,C,L)   16.8 MB
  __bf16* Wqkv = vh + (size_t)B_ * C_ * L_;      // (640,512)  655 KB
  float* bqkv = (float*)(Wqkv + (size_t)640 * C_);  // 640 fp32
  // sinv overlays xTh (dead after gemm_qkv) -> no net workspace growth
  float* sinv = (float*)xTh;                     // (B,L) fp32  64 KB

  dim3 blk(256);
  transpose_cvt<<<dim3(L_ / 32, C_ / 32, B_), blk, 0, stream>>>(x, xTh);
  prep_qkv<<<dim3(320), blk, 0, stream>>>(Wq, Wk, Wv, bq, bk, bv, Wqkv, bqkv);
  // [q;k;v] = Wqkv (640x512) * xT^T, epilogue-routed
  gemm_qkv<<<dim3(5, L_ / 128, B_), blk, 0, stream>>>(Wqkv, xTh, bqkv, qh, kh,
                                                      vh);
  row_sums<<<dim3(64, B_), blk, 0, stream>>>(qh, kh, dmask, sinv);
  attn_fused<<<dim3(64, B_), blk, 0, stream>>>(qh, kh, vh, dmask, sinv, att,
                                               out);
}

// Round 8
// 427.282 us; speedup vs baseline: 1.1332x; 1.1332x over previous
//
#include <hip/hip_runtime.h>
#include <cstddef>
#include <math.h>

#define B_ 8
#define C_ 512
#define L_ 2048
#define D_ 64

typedef __bf16 bf16x8 __attribute__((ext_vector_type(8)));
typedef __bf16 bf16x4 __attribute__((ext_vector_type(4)));
typedef float f32x4 __attribute__((ext_vector_type(4)));

#define MFMA16 __builtin_amdgcn_mfma_f32_16x16x32_bf16

__device__ __forceinline__ void async_lds16(const void* g, void* l) {
  __builtin_amdgcn_global_load_lds(
      (const __attribute__((address_space(1))) void*)g,
      (__attribute__((address_space(3))) void*)l, 16, 0, 0);
}

// ---------------------------------------------------------------------------
// x (B,C,L) fp32 -> xT (B,L,C) bf16. 64c x 64l tiles, float4 reads,
// LDS transpose, bf16x8 stores (4 lanes = one full 128B line per xT row).
// Round-8 rewrite: old version used scalar 4B loads + scalar 2B stores (G13).
// ---------------------------------------------------------------------------
__global__ __launch_bounds__(256) void transpose_cvt(const float* __restrict__ x,
                                                     __bf16* __restrict__ xT) {
  __shared__ float ts[64][68];  // stride 68: b128-aligned rows
  const int b = blockIdx.z;
  const int l0 = blockIdx.x * 64, c0 = blockIdx.y * 64;
  const int t = threadIdx.x;
  const float* xb = x + ((size_t)b * C_ + c0) * L_ + l0;
  // stage: 64 c-rows x 64 l (1024 float4), coalesced reads, b128 LDS writes
#pragma unroll
  for (int kq = 0; kq < 4; ++kq) {
    const int i = t + kq * 256;
    const int row = i >> 4, col4 = i & 15;
    const float4 v = *(const float4*)(xb + (size_t)row * L_ + col4 * 4);
    *(f32x4*)&ts[row][col4 * 4] = *(const f32x4*)&v;
  }
  __syncthreads();
  // write: row l of xT, 4 lanes x 32B = 128B contiguous per row
  __bf16* xTb = xT + ((size_t)b * L_ + l0) * C_ + c0;
  const int l = t >> 2, cq = (t & 3) * 16;
  bf16x8 o0, o1;
#pragma unroll
  for (int j = 0; j < 8; ++j) o0[j] = (__bf16)ts[cq + j][l];
#pragma unroll
  for (int j = 0; j < 8; ++j) o1[j] = (__bf16)ts[cq + 8 + j][l];
  *(bf16x8*)(xTb + (size_t)l * C_ + cq) = o0;
  *(bf16x8*)(xTb + (size_t)l * C_ + cq + 8) = o1;
}

// ---------------------------------------------------------------------------
// Stack [Wq;Wk;Wv] -> W bf16 (640x512), [bq;bk;bv] -> bias fp32 (640)
// ---------------------------------------------------------------------------
__global__ __launch_bounds__(256) void prep_qkv(
    const float* __restrict__ Wq, const float* __restrict__ Wk,
    const float* __restrict__ Wv, const float* __restrict__ bq,
    const float* __restrict__ bk, const float* __restrict__ bv,
    __bf16* __restrict__ W, float* __restrict__ bias) {
  const int i = blockIdx.x * 256 + threadIdx.x;  // float4 index, 81920 total
  const int rq = 64 * 512 / 4;                   // 8192
  const int rk = 128 * 512 / 4;                  // 16384
  const float* src;
  int j;
  if (i < rq) {
    src = Wq; j = i;
  } else if (i < rk) {
    src = Wk; j = i - rq;
  } else {
    src = Wv; j = i - rk;
  }
  float4 v = ((const float4*)src)[j];
  bf16x4 h = {(__bf16)v.x, (__bf16)v.y, (__bf16)v.z, (__bf16)v.w};
  ((bf16x4*)W)[i] = h;
  if (blockIdx.x == 0) {
    for (int t = threadIdx.x; t < 640; t += 256)
      bias[t] = t < 64 ? bq[t] : (t < 128 ? bk[t - 64] : bv[t - 128]);
  }
}

// ---------------------------------------------------------------------------
// Unified MFMA bf16 gemm_bt: C[m,n] = sum_k W[m,k]*xT[n,k] + bias[m]
// M=640 stacked [q(64); k(64); v(512)], N=L, K=C. 128x128 tile, BK=32,
// XOR-swizzled LDS chunks. Epilogue routes rows to qh/kh/vh.
// ---------------------------------------------------------------------------
__global__ __launch_bounds__(256) void gemm_qkv(
    const __bf16* __restrict__ A, const __bf16* __restrict__ Bm,
    const float* __restrict__ bias, __bf16* __restrict__ qh,
    __bf16* __restrict__ kh, __bf16* __restrict__ vh) {
  __shared__ __align__(16) __bf16 Ash[128 * 32];
  __shared__ __align__(16) __bf16 Bsh[128 * 32];
  const int b = blockIdx.z;
  const int m0 = blockIdx.x * 128;
  const int n0 = blockIdx.y * 128;
  const int tid = threadIdx.x;
  const int w = tid >> 6, lane = tid & 63;
  const int wm = (w & 1) * 64, wn = (w >> 1) * 64;
  const int lm = lane & 15, q8 = lane >> 4;
  const int srow = lane >> 2;                      // row within 16-row group
  const int sk8 = (lane & 3) ^ ((lane >> 3) & 3);  // swizzled source chunk

  const __bf16* Bb = Bm + (size_t)b * L_ * C_;
  f32x4 acc[4][4] = {};

  for (int k0 = 0; k0 < C_; k0 += 32) {
#pragma unroll
    for (int t = 0; t < 2; ++t) {
      const int rb = (t * 4 + w) * 16;
      async_lds16(A + (size_t)(m0 + rb + srow) * C_ + k0 + sk8 * 8,
                  &Ash[rb * 32]);
      async_lds16(Bb + (size_t)(n0 + rb + srow) * C_ + k0 + sk8 * 8,
                  &Bsh[rb * 32]);
    }
    __syncthreads();
    const int swz = (q8 ^ ((lm >> 1) & 3)) * 8;
    bf16x8 afr[4], bfr[4];
#pragma unroll
    for (int i = 0; i < 4; ++i) {
      afr[i] = *(const bf16x8*)&Ash[(wm + i * 16 + lm) * 32 + swz];
      bfr[i] = *(const bf16x8*)&Bsh[(wn + i * 16 + lm) * 32 + swz];
    }
#pragma unroll
    for (int i = 0; i < 4; ++i)
#pragma unroll
      for (int j = 0; j < 4; ++j)
        acc[i][j] = MFMA16(afr[i], bfr[j], acc[i][j], 0, 0, 0);
    __syncthreads();
  }

#pragma unroll
  for (int i = 0; i < 4; ++i) {
#pragma unroll
    for (int j = 0; j < 4; ++j) {
      const int ng = n0 + wn + j * 16 + lm;
      const int mg = m0 + wm + i * 16 + q8 * 4;  // global stacked row (4-group)
      if (mg < 128) {
        bf16x4 h;
#pragma unroll
        for (int r = 0; r < 4; ++r) h[r] = (__bf16)(acc[i][j][r] + bias[mg + r]);
        if (mg < 64)
          *(bf16x4*)&qh[((size_t)b * L_ + ng) * 64 + mg] = h;
        else
          *(bf16x4*)&kh[((size_t)b * L_ + ng) * 64 + mg - 64] = h;
      } else {
#pragma unroll
        for (int r = 0; r < 4; ++r)
          vh[((size_t)b * C_ + mg - 128 + r) * L_ + ng] =
              (__bf16)(acc[i][j][r] + bias[mg + r]);
      }
    }
  }
}

// ---------------------------------------------------------------------------
// Row sums of exp(QK^T) under causal+data mask -> sinv[b*L+l] = 1/rowsum.
// Identical QK/exp code path to attn_fused => bit-identical normalization.
// One block per 32-row stripe (balanced s mapping), k/mask double-buffered.
// ---------------------------------------------------------------------------
__global__ __launch_bounds__(256) void row_sums(
    const __bf16* __restrict__ q, const __bf16* __restrict__ k,
    const unsigned char* __restrict__ mask, float* __restrict__ sinv) {
  __shared__ __align__(16) __bf16 qs[32 * 64];
  __shared__ __align__(16) __bf16 ks[2][128 * 64];
  __shared__ __align__(16) unsigned char msk[2][32 * 128];
  __shared__ float sums[4][32];
  const int b = blockIdx.y;
  const int s = (b < 4) ? (int)blockIdx.x : 63 - (int)blockIdx.x;
  const int r0 = s * 32;
  const int T = (r0 + 31) / 128 + 1;
  const int tid = threadIdx.x;
  const int w = tid >> 6, lane = tid & 63;
  const int lm = lane & 15, q8 = lane >> 4;
  const __bf16* qb = q + (size_t)b * L_ * D_;
  const __bf16* kb = k + (size_t)b * L_ * D_;
  const int krow = lane >> 3;
  const int kk8 = (lane & 7) ^ ((lane >> 3) & 7);

  async_lds16(qb + (size_t)r0 * D_ + tid * 8, &qs[w * 512]);
#pragma unroll
  for (int r = 0; r < 4; ++r)
    async_lds16(kb + (size_t)(r * 32 + w * 8 + krow) * 64 + kk8 * 8,
                &ks[0][(r * 32 + w * 8) * 64]);
  async_lds16(mask + ((size_t)b * L_ + r0 + w * 8 + krow) * L_ + (lane & 7) * 16,
              &msk[0][w * 1024]);

  bf16x8 af[2][2];
  float rsum[2][4] = {};
  for (int t = 0; t < T; ++t) {
    const int t0 = t * 128, buf = t & 1;
    __syncthreads();
    if (t == 0) {
#pragma unroll
      for (int i = 0; i < 2; ++i)
#pragma unroll
        for (int kk = 0; kk < 2; ++kk)
          af[i][kk] = *(const bf16x8*)&qs[(i * 16 + lm) * 64 + kk * 32 + q8 * 8];
    }
    if (t + 1 < T) {
      const int nt0 = t0 + 128, nb = (t + 1) & 1;
#pragma unroll
      for (int r = 0; r < 4; ++r)
        async_lds16(kb + (size_t)(nt0 + r * 32 + w * 8 + krow) * 64 + kk8 * 8,
                    &ks[nb][(r * 32 + w * 8) * 64]);
      async_lds16(mask + ((size_t)b * L_ + r0 + w * 8 + krow) * L_ + nt0 +
                      (lane & 7) * 16,
                  &msk[nb][w * 1024]);
    }
    f32x4 acc[2][2] = {};
#pragma unroll
    for (int kk = 0; kk < 2; ++kk) {
#pragma unroll
      for (int j = 0; j < 2; ++j) {
        const int n = w * 32 + j * 16 + lm;
        const int k8i = kk * 4 + q8;
        bf16x8 bf = *(const bf16x8*)&ks[buf][n * 64 + ((k8i ^ (n & 7)) * 8)];
#pragma unroll
        for (int i = 0; i < 2; ++i)
          acc[i][j] = MFMA16(af[i][kk], bf, acc[i][j], 0, 0, 0);
      }
    }
#pragma unroll
    for (int i = 0; i < 2; ++i)
#pragma unroll
      for (int j = 0; j < 2; ++j)
#pragma unroll
        for (int r = 0; r < 4; ++r) {
          const int lr = i * 16 + q8 * 4 + r;
          const int mcol = w * 32 + j * 16 + lm;
          const int l = r0 + lr, m = t0 + mcol;
          const bool ok = (m <= l) && (msk[buf][lr * 128 + mcol] == 0);
          rsum[i][r] += ok ? __expf(acc[i][j][r]) : 0.f;
        }
  }
  // reduce across the 16 col-lanes, then across the 4 waves
#pragma unroll
  for (int i = 0; i < 2; ++i)
#pragma unroll
    for (int r = 0; r < 4; ++r) {
      float vv = rsum[i][r];
      vv += __shfl_xor(vv, 1);
      vv += __shfl_xor(vv, 2);
      vv += __shfl_xor(vv, 4);
      vv += __shfl_xor(vv, 8);
      if (lm == 0) sums[w][i * 16 + q8 * 4 + r] = vv;
    }
  __syncthreads();
  if (tid < 32)
    sinv[(size_t)b * L_ + r0 + tid] =
        1.f / (sums[0][tid] + sums[1][tid] + sums[2][tid] + sums[3][tid]);
}

// ---------------------------------------------------------------------------
// Single-pass fused attention (round-6 internals, verified 119.5us).
// Round-8 delta: XCD-batch swizzle -- gid&7 = b so all 64 stripe-blocks of
// batch b land on XCD b (64 blocks = 64 block-slots/XCD at 2 blocks/CU);
// v[b] (2MB) + k[b] then stay resident in that XCD's 4MB L2 instead of all
// 8 batches (16MB) thrashing every L2. Long/short stripes paired per CU.
// Mid-tile barrier stays lgkmcnt-only; V reads inline in PV (L2-resident).
// ---------------------------------------------------------------------------
__global__ __launch_bounds__(256) void attn_fused(
    const __bf16* __restrict__ q, const __bf16* __restrict__ k,
    const __bf16* __restrict__ v, const unsigned char* __restrict__ mask,
    const float* __restrict__ sinv, float* __restrict__ att,
    float* __restrict__ out) {
  __shared__ __align__(16) __bf16 qs[32 * 64];              // 4 KB
  __shared__ __align__(16) __bf16 ks[2][128 * 64];          // 32 KB, swizzled
  __shared__ __align__(16) unsigned char msk[2][32 * 128];  // 8 KB
  __shared__ __align__(16) __bf16 Ps[32 * 136];             // 8.5 KB, padded
  const int gid = blockIdx.x;
  const int b = gid & 7;        // batch == XCD (round-robin dispatch)
  const int s0 = gid >> 3;
  const int s = (s0 & 1) ? 63 - (s0 >> 1) : (s0 >> 1);  // pair long+short
  const int r0 = s * 32;
  const int T = (r0 + 31) / 128 + 1;  // tiles with any unmasked col
  const int tid = threadIdx.x;
  const int w = tid >> 6, lane = tid & 63;
  const int lm = lane & 15, q8 = lane >> 4;
  const __bf16* qb = q + (size_t)b * L_ * D_;
  const __bf16* kb = k + (size_t)b * L_ * D_;
  const __bf16* vb = v + (size_t)b * C_ * L_;
  const int krow = lane >> 3;
  const int kk8 = (lane & 7) ^ ((lane >> 3) & 7);

  float inv[2][4];
#pragma unroll
  for (int i = 0; i < 2; ++i)
#pragma unroll
    for (int r = 0; r < 4; ++r)
      inv[i][r] = sinv[(size_t)b * L_ + r0 + i * 16 + q8 * 4 + r];

  bf16x8 af[2][2];
  f32x4 accO[2][8] = {};  // 32 rows x 128 channels per wave

  async_lds16(qb + (size_t)r0 * D_ + tid * 8, &qs[w * 512]);
#pragma unroll
  for (int r = 0; r < 4; ++r)
    async_lds16(kb + (size_t)(r * 32 + w * 8 + krow) * 64 + kk8 * 8,
                &ks[0][(r * 32 + w * 8) * 64]);
  async_lds16(mask + ((size_t)b * L_ + r0 + w * 8 + krow) * L_ + (lane & 7) * 16,
              &msk[0][w * 1024]);

  for (int t = 0; t < T; ++t) {
    const int t0 = t * 128, buf = t & 1;
    __syncthreads();  // buf tiles (and on t==0: qs) ready
    if (t == 0) {
#pragma unroll
      for (int i = 0; i < 2; ++i)
#pragma unroll
        for (int kk = 0; kk < 2; ++kk)
          af[i][kk] = *(const bf16x8*)&qs[(i * 16 + lm) * 64 + kk * 32 + q8 * 8];
    }
    if (t + 1 < T) {  // prefetch next tile into the other buffer
      const int nt0 = t0 + 128, nb = (t + 1) & 1;
#pragma unroll
      for (int r = 0; r < 4; ++r)
        async_lds16(kb + (size_t)(nt0 + r * 32 + w * 8 + krow) * 64 + kk8 * 8,
                    &ks[nb][(r * 32 + w * 8) * 64]);
      async_lds16(mask + ((size_t)b * L_ + r0 + w * 8 + krow) * L_ + nt0 +
                      (lane & 7) * 16,
                  &msk[nb][w * 1024]);
    }
    // ---- QK^T MFMA (swizzled B-frag reads) ----
    f32x4 acc[2][2] = {};
#pragma unroll
    for (int kk = 0; kk < 2; ++kk) {
#pragma unroll
      for (int j = 0; j < 2; ++j) {
        const int n = w * 32 + j * 16 + lm;
        const int k8i = kk * 4 + q8;
        bf16x8 bf = *(const bf16x8*)&ks[buf][n * 64 + ((k8i ^ (n & 7)) * 8)];
#pragma unroll
        for (int i = 0; i < 2; ++i)
          acc[i][j] = MFMA16(af[i][kk], bf, acc[i][j], 0, 0, 0);
      }
    }
    // ---- exp + mask + att write (normalized) + P to LDS (unnormalized) ----
#pragma unroll
    for (int i = 0; i < 2; ++i)
#pragma unroll
      for (int j = 0; j < 2; ++j)
#pragma unroll
        for (int r = 0; r < 4; ++r) {
          const int lr = i * 16 + q8 * 4 + r;
          const int mcol = w * 32 + j * 16 + lm;
          const int l = r0 + lr, m = t0 + mcol;
          const bool ok = (m <= l) && (msk[buf][lr * 128 + mcol] == 0);
          const float p = ok ? __expf(acc[i][j][r]) : 0.f;
          att[((size_t)b * L_ + l) * L_ + m] = p * inv[i][r];
          Ps[lr * 136 + mcol] = (__bf16)p;
        }
    // Ps-ready barrier: LDS-only drain; att stores + k/mask prefetches stay
    // in flight (no vmcnt(0) here -- that drain was the per-tile stall).
    asm volatile("s_waitcnt lgkmcnt(0)\n\ts_barrier" ::: "memory");
    __builtin_amdgcn_sched_barrier(0);
    // ---- PV: A = P rows (32 x 128k), B = v (wave's 128 channels) ----
#pragma unroll
    for (int kk = 0; kk < 4; ++kk) {
      bf16x8 pa[2];
#pragma unroll
      for (int i = 0; i < 2; ++i)
        pa[i] = *(const bf16x8*)&Ps[(i * 16 + lm) * 136 + kk * 32 + q8 * 8];
#pragma unroll
      for (int cf = 0; cf < 8; ++cf) {
        const int c = w * 128 + cf * 16 + lm;
        bf16x8 bv =
            *(const bf16x8*)(vb + (size_t)c * L_ + t0 + kk * 32 + q8 * 8);
#pragma unroll
        for (int i = 0; i < 2; ++i)
          accO[i][cf] = MFMA16(pa[i], bv, accO[i][cf], 0, 0, 0);
      }
    }
  }

  // ---- out epilogue: scale by inv[row], vectorized along l ----
#pragma unroll
  for (int i = 0; i < 2; ++i)
#pragma unroll
    for (int cf = 0; cf < 8; ++cf) {
      const int c = w * 128 + cf * 16 + lm;
      f32x4 o;
      o[0] = accO[i][cf][0] * inv[i][0];
      o[1] = accO[i][cf][1] * inv[i][1];
      o[2] = accO[i][cf][2] * inv[i][2];
      o[3] = accO[i][cf][3] * inv[i][3];
      *(f32x4*)(out + ((size_t)b * C_ + c) * L_ + r0 + i * 16 + q8 * 4) = o;
    }

  // ---- zero-fill att cols [T*128, L) of this stripe ----
  const f32x4 z4 = {0.f, 0.f, 0.f, 0.f};
  for (int rr = 0; rr < 32; ++rr) {
    float* arow = att + ((size_t)b * L_ + r0 + rr) * L_;
    for (int c = T * 128 + tid * 4; c < L_; c += 1024) *(f32x4*)&arow[c] = z4;
  }
}

// ---------------------------------------------------------------------------
extern "C" void kernel_launch(void* const* d_in, const int* in_sizes, int n_in,
                              void* d_out, int out_size, void* d_ws,
                              size_t ws_size, hipStream_t stream) {
  const float* x = (const float*)d_in[0];
  const unsigned char* dmask = (const unsigned char*)d_in[1];
  const float* Wq = (const float*)d_in[2];
  const float* bq = (const float*)d_in[3];
  const float* Wk = (const float*)d_in[4];
  const float* bk = (const float*)d_in[5];
  const float* Wv = (const float*)d_in[6];
  const float* bv = (const float*)d_in[7];

  float* out = (float*)d_out;               // (B, C, L)
  float* att = out + (size_t)B_ * C_ * L_;  // (B, L, L)

  __bf16* qh = (__bf16*)d_ws;                    // (B,L,64)   2 MB
  __bf16* kh = qh + (size_t)B_ * L_ * D_;        // (B,L,64)   2 MB
  __bf16* xTh = kh + (size_t)B_ * L_ * D_;       // (B,L,C)   16.8 MB
  __bf16* vh = xTh + (size_t)B_ * L_ * C_;       // (B,C,L)   16.8 MB
  __bf16* Wqkv = vh + (size_t)B_ * C_ * L_;      // (640,512)  655 KB
  float* bqkv = (float*)(Wqkv + (size_t)640 * C_);  // 640 fp32
  // sinv overlays xTh (dead after gemm_qkv) -> no net workspace growth
  float* sinv = (float*)xTh;                     // (B,L) fp32  64 KB

  dim3 blk(256);
  transpose_cvt<<<dim3(L_ / 64, C_ / 64, B_), blk, 0, stream>>>(x, xTh);
  prep_qkv<<<dim3(320), blk, 0, stream>>>(Wq, Wk, Wv, bq, bk, bv, Wqkv, bqkv);
  // [q;k;v] = Wqkv (640x512) * xT^T, epilogue-routed
  gemm_qkv<<<dim3(5, L_ / 128, B_), blk, 0, stream>>>(Wqkv, xTh, bqkv, qh, kh,
                                                      vh);
  row_sums<<<dim3(64, B_), blk, 0, stream>>>(qh, kh, dmask, sinv);
  attn_fused<<<dim3(512), blk, 0, stream>>>(qh, kh, vh, dmask, sinv, att, out);
}

// Round 9
// 406.856 us; speedup vs baseline: 1.1901x; 1.0502x over previous
//
#include <hip/hip_runtime.h>
#include <cstddef>
#include <math.h>

#define B_ 8
#define C_ 512
#define L_ 2048
#define D_ 64

typedef __bf16 bf16x8 __attribute__((ext_vector_type(8)));
typedef __bf16 bf16x4 __attribute__((ext_vector_type(4)));
typedef float f32x4 __attribute__((ext_vector_type(4)));

#define MFMA16 __builtin_amdgcn_mfma_f32_16x16x32_bf16

__device__ __forceinline__ void async_lds16(const void* g, void* l) {
  __builtin_amdgcn_global_load_lds(
      (const __attribute__((address_space(1))) void*)g,
      (__attribute__((address_space(3))) void*)l, 16, 0, 0);
}

// ---------------------------------------------------------------------------
// x (B,C,L) fp32 -> xT (B,L,C) bf16. 64c x 64l tiles, float4 reads,
// LDS transpose, bf16x8 stores (4 lanes = one full 128B line per xT row).
// ---------------------------------------------------------------------------
__global__ __launch_bounds__(256) void transpose_cvt(const float* __restrict__ x,
                                                     __bf16* __restrict__ xT) {
  __shared__ float ts[64][68];  // stride 68: b128-aligned rows
  const int b = blockIdx.z;
  const int l0 = blockIdx.x * 64, c0 = blockIdx.y * 64;
  const int t = threadIdx.x;
  const float* xb = x + ((size_t)b * C_ + c0) * L_ + l0;
  // stage: 64 c-rows x 64 l (1024 float4), coalesced reads, b128 LDS writes
#pragma unroll
  for (int kq = 0; kq < 4; ++kq) {
    const int i = t + kq * 256;
    const int row = i >> 4, col4 = i & 15;
    const float4 v = *(const float4*)(xb + (size_t)row * L_ + col4 * 4);
    *(f32x4*)&ts[row][col4 * 4] = *(const f32x4*)&v;
  }
  __syncthreads();
  // write: row l of xT, 4 lanes x 32B = 128B contiguous per row
  __bf16* xTb = xT + ((size_t)b * L_ + l0) * C_ + c0;
  const int l = t >> 2, cq = (t & 3) * 16;
  bf16x8 o0, o1;
#pragma unroll
  for (int j = 0; j < 8; ++j) o0[j] = (__bf16)ts[cq + j][l];
#pragma unroll
  for (int j = 0; j < 8; ++j) o1[j] = (__bf16)ts[cq + 8 + j][l];
  *(bf16x8*)(xTb + (size_t)l * C_ + cq) = o0;
  *(bf16x8*)(xTb + (size_t)l * C_ + cq + 8) = o1;
}

// ---------------------------------------------------------------------------
// Stack [Wq;Wk;Wv] -> W bf16 (640x512), [bq;bk;bv] -> bias fp32 (640)
// ---------------------------------------------------------------------------
__global__ __launch_bounds__(256) void prep_qkv(
    const float* __restrict__ Wq, const float* __restrict__ Wk,
    const float* __restrict__ Wv, const float* __restrict__ bq,
    const float* __restrict__ bk, const float* __restrict__ bv,
    __bf16* __restrict__ W, float* __restrict__ bias) {
  const int i = blockIdx.x * 256 + threadIdx.x;  // float4 index, 81920 total
  const int rq = 64 * 512 / 4;                   // 8192
  const int rk = 128 * 512 / 4;                  // 16384
  const float* src;
  int j;
  if (i < rq) {
    src = Wq; j = i;
  } else if (i < rk) {
    src = Wk; j = i - rq;
  } else {
    src = Wv; j = i - rk;
  }
  float4 v = ((const float4*)src)[j];
  bf16x4 h = {(__bf16)v.x, (__bf16)v.y, (__bf16)v.z, (__bf16)v.w};
  ((bf16x4*)W)[i] = h;
  if (blockIdx.x == 0) {
    for (int t = threadIdx.x; t < 640; t += 256)
      bias[t] = t < 64 ? bq[t] : (t < 128 ? bk[t - 64] : bv[t - 128]);
  }
}

// ---------------------------------------------------------------------------
// Unified MFMA bf16 gemm_bt: C[m,n] = sum_k W[m,k]*xT[n,k] + bias[m]
// M=640 stacked [q(64); k(64); v(512)], N=L, K=C. 128x128 tile, BK=32,
// XOR-swizzled LDS chunks. Epilogue routes rows to qh/kh/vh.
// ---------------------------------------------------------------------------
__global__ __launch_bounds__(256) void gemm_qkv(
    const __bf16* __restrict__ A, const __bf16* __restrict__ Bm,
    const float* __restrict__ bias, __bf16* __restrict__ qh,
    __bf16* __restrict__ kh, __bf16* __restrict__ vh) {
  __shared__ __align__(16) __bf16 Ash[128 * 32];
  __shared__ __align__(16) __bf16 Bsh[128 * 32];
  const int b = blockIdx.z;
  const int m0 = blockIdx.x * 128;
  const int n0 = blockIdx.y * 128;
  const int tid = threadIdx.x;
  const int w = tid >> 6, lane = tid & 63;
  const int wm = (w & 1) * 64, wn = (w >> 1) * 64;
  const int lm = lane & 15, q8 = lane >> 4;
  const int srow = lane >> 2;                      // row within 16-row group
  const int sk8 = (lane & 3) ^ ((lane >> 3) & 3);  // swizzled source chunk

  const __bf16* Bb = Bm + (size_t)b * L_ * C_;
  f32x4 acc[4][4] = {};

  for (int k0 = 0; k0 < C_; k0 += 32) {
#pragma unroll
    for (int t = 0; t < 2; ++t) {
      const int rb = (t * 4 + w) * 16;
      async_lds16(A + (size_t)(m0 + rb + srow) * C_ + k0 + sk8 * 8,
                  &Ash[rb * 32]);
      async_lds16(Bb + (size_t)(n0 + rb + srow) * C_ + k0 + sk8 * 8,
                  &Bsh[rb * 32]);
    }
    __syncthreads();
    const int swz = (q8 ^ ((lm >> 1) & 3)) * 8;
    bf16x8 afr[4], bfr[4];
#pragma unroll
    for (int i = 0; i < 4; ++i) {
      afr[i] = *(const bf16x8*)&Ash[(wm + i * 16 + lm) * 32 + swz];
      bfr[i] = *(const bf16x8*)&Bsh[(wn + i * 16 + lm) * 32 + swz];
    }
#pragma unroll
    for (int i = 0; i < 4; ++i)
#pragma unroll
      for (int j = 0; j < 4; ++j)
        acc[i][j] = MFMA16(afr[i], bfr[j], acc[i][j], 0, 0, 0);
    __syncthreads();
  }

#pragma unroll
  for (int i = 0; i < 4; ++i) {
#pragma unroll
    for (int j = 0; j < 4; ++j) {
      const int ng = n0 + wn + j * 16 + lm;
      const int mg = m0 + wm + i * 16 + q8 * 4;  // global stacked row (4-group)
      if (mg < 128) {
        bf16x4 h;
#pragma unroll
        for (int r = 0; r < 4; ++r) h[r] = (__bf16)(acc[i][j][r] + bias[mg + r]);
        if (mg < 64)
          *(bf16x4*)&qh[((size_t)b * L_ + ng) * 64 + mg] = h;
        else
          *(bf16x4*)&kh[((size_t)b * L_ + ng) * 64 + mg - 64] = h;
      } else {
#pragma unroll
        for (int r = 0; r < 4; ++r)
          vh[((size_t)b * C_ + mg - 128 + r) * L_ + ng] =
              (__bf16)(acc[i][j][r] + bias[mg + r]);
      }
    }
  }
}

// ---------------------------------------------------------------------------
// Row sums of exp(QK^T) under causal+data mask -> sinv[b*L+l] = 1/rowsum.
// Identical QK/exp code path to attn_fused => bit-identical normalization.
// ---------------------------------------------------------------------------
__global__ __launch_bounds__(256) void row_sums(
    const __bf16* __restrict__ q, const __bf16* __restrict__ k,
    const unsigned char* __restrict__ mask, float* __restrict__ sinv) {
  __shared__ __align__(16) __bf16 qs[32 * 64];
  __shared__ __align__(16) __bf16 ks[2][128 * 64];
  __shared__ __align__(16) unsigned char msk[2][32 * 128];
  __shared__ float sums[4][32];
  const int b = blockIdx.y;
  const int s = (b < 4) ? (int)blockIdx.x : 63 - (int)blockIdx.x;
  const int r0 = s * 32;
  const int T = (r0 + 31) / 128 + 1;
  const int tid = threadIdx.x;
  const int w = tid >> 6, lane = tid & 63;
  const int lm = lane & 15, q8 = lane >> 4;
  const __bf16* qb = q + (size_t)b * L_ * D_;
  const __bf16* kb = k + (size_t)b * L_ * D_;
  const int krow = lane >> 3;
  const int kk8 = (lane & 7) ^ ((lane >> 3) & 7);

  async_lds16(qb + (size_t)r0 * D_ + tid * 8, &qs[w * 512]);
#pragma unroll
  for (int r = 0; r < 4; ++r)
    async_lds16(kb + (size_t)(r * 32 + w * 8 + krow) * 64 + kk8 * 8,
                &ks[0][(r * 32 + w * 8) * 64]);
  async_lds16(mask + ((size_t)b * L_ + r0 + w * 8 + krow) * L_ + (lane & 7) * 16,
              &msk[0][w * 1024]);

  bf16x8 af[2][2];
  float rsum[2][4] = {};
  for (int t = 0; t < T; ++t) {
    const int t0 = t * 128, buf = t & 1;
    __syncthreads();
    if (t == 0) {
#pragma unroll
      for (int i = 0; i < 2; ++i)
#pragma unroll
        for (int kk = 0; kk < 2; ++kk)
          af[i][kk] = *(const bf16x8*)&qs[(i * 16 + lm) * 64 + kk * 32 + q8 * 8];
    }
    if (t + 1 < T) {
      const int nt0 = t0 + 128, nb = (t + 1) & 1;
#pragma unroll
      for (int r = 0; r < 4; ++r)
        async_lds16(kb + (size_t)(nt0 + r * 32 + w * 8 + krow) * 64 + kk8 * 8,
                    &ks[nb][(r * 32 + w * 8) * 64]);
      async_lds16(mask + ((size_t)b * L_ + r0 + w * 8 + krow) * L_ + nt0 +
                      (lane & 7) * 16,
                  &msk[nb][w * 1024]);
    }
    f32x4 acc[2][2] = {};
#pragma unroll
    for (int kk = 0; kk < 2; ++kk) {
#pragma unroll
      for (int j = 0; j < 2; ++j) {
        const int n = w * 32 + j * 16 + lm;
        const int k8i = kk * 4 + q8;
        bf16x8 bf = *(const bf16x8*)&ks[buf][n * 64 + ((k8i ^ (n & 7)) * 8)];
#pragma unroll
        for (int i = 0; i < 2; ++i)
          acc[i][j] = MFMA16(af[i][kk], bf, acc[i][j], 0, 0, 0);
      }
    }
#pragma unroll
    for (int i = 0; i < 2; ++i)
#pragma unroll
      for (int j = 0; j < 2; ++j)
#pragma unroll
        for (int r = 0; r < 4; ++r) {
          const int lr = i * 16 + q8 * 4 + r;
          const int mcol = w * 32 + j * 16 + lm;
          const int l = r0 + lr, m = t0 + mcol;
          const bool ok = (m <= l) && (msk[buf][lr * 128 + mcol] == 0);
          rsum[i][r] += ok ? __expf(acc[i][j][r]) : 0.f;
        }
  }
  // reduce across the 16 col-lanes, then across the 4 waves
#pragma unroll
  for (int i = 0; i < 2; ++i)
#pragma unroll
    for (int r = 0; r < 4; ++r) {
      float vv = rsum[i][r];
      vv += __shfl_xor(vv, 1);
      vv += __shfl_xor(vv, 2);
      vv += __shfl_xor(vv, 4);
      vv += __shfl_xor(vv, 8);
      if (lm == 0) sums[w][i * 16 + q8 * 4 + r] = vv;
    }
  __syncthreads();
  if (tid < 32)
    sinv[(size_t)b * L_ + r0 + tid] =
        1.f / (sums[0][tid] + sums[1][tid] + sums[2][tid] + sums[3][tid]);
}

// ---------------------------------------------------------------------------
// Single-pass fused attention (round-6 internals). Round-9 delta vs round 8:
// keep the XCD-batch swizzle (b = gid&7: FETCH 92->19MB, confirmed) but fix
// the stripe mapping so co-resident CU slots (gid, gid+256) get COMPLEMENTARY
// stripes: s = s0<32 ? s0 : 95-s0 pairs s with 63-s on the same CU ->
// per-CU work T(s)+T(63-s) ~= 17 tiles flat (round-8's s0/2 interleave gave
// pairs up to 28 tiles -> 1.65x tail, the 145us regression).
// ---------------------------------------------------------------------------
__global__ __launch_bounds__(256) void attn_fused(
    const __bf16* __restrict__ q, const __bf16* __restrict__ k,
    const __bf16* __restrict__ v, const unsigned char* __restrict__ mask,
    const float* __restrict__ sinv, float* __restrict__ att,
    float* __restrict__ out) {
  __shared__ __align__(16) __bf16 qs[32 * 64];              // 4 KB
  __shared__ __align__(16) __bf16 ks[2][128 * 64];          // 32 KB, swizzled
  __shared__ __align__(16) unsigned char msk[2][32 * 128];  // 8 KB
  __shared__ __align__(16) __bf16 Ps[32 * 136];             // 8.5 KB, padded
  const int gid = blockIdx.x;
  const int b = gid & 7;     // batch == XCD (round-robin dispatch, confirmed)
  const int s0 = gid >> 3;
  const int s = (s0 < 32) ? s0 : 95 - s0;  // slots (s0, s0+32) -> (s, 63-s)
  const int r0 = s * 32;
  const int T = (r0 + 31) / 128 + 1;  // tiles with any unmasked col
  const int tid = threadIdx.x;
  const int w = tid >> 6, lane = tid & 63;
  const int lm = lane & 15, q8 = lane >> 4;
  const __bf16* qb = q + (size_t)b * L_ * D_;
  const __bf16* kb = k + (size_t)b * L_ * D_;
  const __bf16* vb = v + (size_t)b * C_ * L_;
  const int krow = lane >> 3;
  const int kk8 = (lane & 7) ^ ((lane >> 3) & 7);

  float inv[2][4];
#pragma unroll
  for (int i = 0; i < 2; ++i)
#pragma unroll
    for (int r = 0; r < 4; ++r)
      inv[i][r] = sinv[(size_t)b * L_ + r0 + i * 16 + q8 * 4 + r];

  bf16x8 af[2][2];
  f32x4 accO[2][8] = {};  // 32 rows x 128 channels per wave

  async_lds16(qb + (size_t)r0 * D_ + tid * 8, &qs[w * 512]);
#pragma unroll
  for (int r = 0; r < 4; ++r)
    async_lds16(kb + (size_t)(r * 32 + w * 8 + krow) * 64 + kk8 * 8,
                &ks[0][(r * 32 + w * 8) * 64]);
  async_lds16(mask + ((size_t)b * L_ + r0 + w * 8 + krow) * L_ + (lane & 7) * 16,
              &msk[0][w * 1024]);

  for (int t = 0; t < T; ++t) {
    const int t0 = t * 128, buf = t & 1;
    __syncthreads();  // buf tiles (and on t==0: qs) ready
    if (t == 0) {
#pragma unroll
      for (int i = 0; i < 2; ++i)
#pragma unroll
        for (int kk = 0; kk < 2; ++kk)
          af[i][kk] = *(const bf16x8*)&qs[(i * 16 + lm) * 64 + kk * 32 + q8 * 8];
    }
    if (t + 1 < T) {  // prefetch next tile into the other buffer
      const int nt0 = t0 + 128, nb = (t + 1) & 1;
#pragma unroll
      for (int r = 0; r < 4; ++r)
        async_lds16(kb + (size_t)(nt0 + r * 32 + w * 8 + krow) * 64 + kk8 * 8,
                    &ks[nb][(r * 32 + w * 8) * 64]);
      async_lds16(mask + ((size_t)b * L_ + r0 + w * 8 + krow) * L_ + nt0 +
                      (lane & 7) * 16,
                  &msk[nb][w * 1024]);
    }
    // ---- QK^T MFMA (swizzled B-frag reads) ----
    f32x4 acc[2][2] = {};
#pragma unroll
    for (int kk = 0; kk < 2; ++kk) {
#pragma unroll
      for (int j = 0; j < 2; ++j) {
        const int n = w * 32 + j * 16 + lm;
        const int k8i = kk * 4 + q8;
        bf16x8 bf = *(const bf16x8*)&ks[buf][n * 64 + ((k8i ^ (n & 7)) * 8)];
#pragma unroll
        for (int i = 0; i < 2; ++i)
          acc[i][j] = MFMA16(af[i][kk], bf, acc[i][j], 0, 0, 0);
      }
    }
    // ---- exp + mask + att write (normalized) + P to LDS (unnormalized) ----
#pragma unroll
    for (int i = 0; i < 2; ++i)
#pragma unroll
      for (int j = 0; j < 2; ++j)
#pragma unroll
        for (int r = 0; r < 4; ++r) {
          const int lr = i * 16 + q8 * 4 + r;
          const int mcol = w * 32 + j * 16 + lm;
          const int l = r0 + lr, m = t0 + mcol;
          const bool ok = (m <= l) && (msk[buf][lr * 128 + mcol] == 0);
          const float p = ok ? __expf(acc[i][j][r]) : 0.f;
          att[((size_t)b * L_ + l) * L_ + m] = p * inv[i][r];
          Ps[lr * 136 + mcol] = (__bf16)p;
        }
    // Ps-ready barrier: LDS-only drain; att stores + k/mask prefetches stay
    // in flight (no vmcnt(0) here -- that drain was the per-tile stall).
    asm volatile("s_waitcnt lgkmcnt(0)\n\ts_barrier" ::: "memory");
    __builtin_amdgcn_sched_barrier(0);
    // ---- PV: A = P rows (32 x 128k), B = v (wave's 128 channels) ----
#pragma unroll
    for (int kk = 0; kk < 4; ++kk) {
      bf16x8 pa[2];
#pragma unroll
      for (int i = 0; i < 2; ++i)
        pa[i] = *(const bf16x8*)&Ps[(i * 16 + lm) * 136 + kk * 32 + q8 * 8];
#pragma unroll
      for (int cf = 0; cf < 8; ++cf) {
        const int c = w * 128 + cf * 16 + lm;
        bf16x8 bv =
            *(const bf16x8*)(vb + (size_t)c * L_ + t0 + kk * 32 + q8 * 8);
#pragma unroll
        for (int i = 0; i < 2; ++i)
          accO[i][cf] = MFMA16(pa[i], bv, accO[i][cf], 0, 0, 0);
      }
    }
  }

  // ---- out epilogue: scale by inv[row], vectorized along l ----
#pragma unroll
  for (int i = 0; i < 2; ++i)
#pragma unroll
    for (int cf = 0; cf < 8; ++cf) {
      const int c = w * 128 + cf * 16 + lm;
      f32x4 o;
      o[0] = accO[i][cf][0] * inv[i][0];
      o[1] = accO[i][cf][1] * inv[i][1];
      o[2] = accO[i][cf][2] * inv[i][2];
      o[3] = accO[i][cf][3] * inv[i][3];
      *(f32x4*)(out + ((size_t)b * C_ + c) * L_ + r0 + i * 16 + q8 * 4) = o;
    }

  // ---- zero-fill att cols [T*128, L) of this stripe ----
  const f32x4 z4 = {0.f, 0.f, 0.f, 0.f};
  for (int rr = 0; rr < 32; ++rr) {
    float* arow = att + ((size_t)b * L_ + r0 + rr) * L_;
    for (int c = T * 128 + tid * 4; c < L_; c += 1024) *(f32x4*)&arow[c] = z4;
  }
}

// ---------------------------------------------------------------------------
extern "C" void kernel_launch(void* const* d_in, const int* in_sizes, int n_in,
                              void* d_out, int out_size, void* d_ws,
                              size_t ws_size, hipStream_t stream) {
  const float* x = (const float*)d_in[0];
  const unsigned char* dmask = (const unsigned char*)d_in[1];
  const float* Wq = (const float*)d_in[2];
  const float* bq = (const float*)d_in[3];
  const float* Wk = (const float*)d_in[4];
  const float* bk = (const float*)d_in[5];
  const float* Wv = (const float*)d_in[6];
  const float* bv = (const float*)d_in[7];

  float* out = (float*)d_out;               // (B, C, L)
  float* att = out + (size_t)B_ * C_ * L_;  // (B, L, L)

  __bf16* qh = (__bf16*)d_ws;                    // (B,L,64)   2 MB
  __bf16* kh = qh + (size_t)B_ * L_ * D_;        // (B,L,64)   2 MB
  __bf16* xTh = kh + (size_t)B_ * L_ * D_;       // (B,L,C)   16.8 MB
  __bf16* vh = xTh + (size_t)B_ * L_ * C_;       // (B,C,L)   16.8 MB
  __bf16* Wqkv = vh + (size_t)B_ * C_ * L_;      // (640,512)  655 KB
  float* bqkv = (float*)(Wqkv + (size_t)640 * C_);  // 640 fp32
  // sinv overlays xTh (dead after gemm_qkv) -> no net workspace growth
  float* sinv = (float*)xTh;                     // (B,L) fp32  64 KB

  dim3 blk(256);
  transpose_cvt<<<dim3(L_ / 64, C_ / 64, B_), blk, 0, stream>>>(x, xTh);
  prep_qkv<<<dim3(320), blk, 0, stream>>>(Wq, Wk, Wv, bq, bk, bv, Wqkv, bqkv);
  // [q;k;v] = Wqkv (640x512) * xT^T, epilogue-routed
  gemm_qkv<<<dim3(5, L_ / 128, B_), blk, 0, stream>>>(Wqkv, xTh, bqkv, qh, kh,
                                                      vh);
  row_sums<<<dim3(64, B_), blk, 0, stream>>>(qh, kh, dmask, sinv);
  attn_fused<<<dim3(512), blk, 0, stream>>>(qh, kh, vh, dmask, sinv, att, out);
}